// Round 2
// baseline (1665.695 us; speedup 1.0000x reference)
//
#include <hip/hip_runtime.h>

// ---- dims (fixed by problem) ----
#define B    32
#define P    196
#define ENC  2048
#define DEC  512
#define ATT  512
#define E    256
#define V    30000
#define L    21
#define T    20   // L-1

typedef unsigned short u16;
typedef __bf16 bf16x8 __attribute__((ext_vector_type(8)));
typedef float  f32x4  __attribute__((ext_vector_type(4)));

__device__ __forceinline__ u16 f2bf(float f) {
    union { float f; unsigned int i; } v; v.f = f;
    unsigned int i = v.i;
    return (u16)((i + 0x7fffu + ((i >> 16) & 1u)) >> 16);
}
__device__ __forceinline__ float bf2f(u16 u) {
    union { unsigned int i; float f; } v; v.i = ((unsigned int)u) << 16; return v.f;
}
__device__ __forceinline__ float wave_sum(float v) {
    #pragma unroll
    for (int o = 32; o > 0; o >>= 1) v += __shfl_down(v, o, 64);
    return v;  // lane 0 holds sum
}
__device__ __forceinline__ float sigf(float x) { return 1.0f / (1.0f + expf(-x)); }

// ---- once: f32 -> bf16 conversion (4 elems/thread) ----
__global__ void k_f2b4(const float* __restrict__ s, u16* __restrict__ d, int n4) {
    int i = blockIdx.x * 256 + threadIdx.x;
    if (i < n4) {
        float4 v = reinterpret_cast<const float4*>(s)[i];
        ushort4 o;
        o.x = f2bf(v.x); o.y = f2bf(v.y); o.z = f2bf(v.z); o.w = f2bf(v.w);
        reinterpret_cast<ushort4*>(d)[i] = o;
    }
}

// ---- once: mean over P of encoder_out (f32) -> f32 [B,ENC] ----
__global__ void k_mean(const float* __restrict__ enc, float* __restrict__ mean) {
    int idx = blockIdx.x * 256 + threadIdx.x;        // 65536
    int b = idx >> 11, e = idx & 2047;
    const float* p = enc + (size_t)b * P * ENC + e;
    float s = 0.f;
    for (int i = 0; i < P; i++) s += p[(size_t)i * ENC];
    mean[idx] = s * (1.0f / 196.0f);
}

// ---- once: h0/c0 = mean @ W^T + b  (f32 dot, wave per output) ----
__global__ void k_h0c0(const float* __restrict__ mean,
                       const float* __restrict__ Wh0, const float* __restrict__ bh0,
                       const float* __restrict__ Wc0, const float* __restrict__ bc0,
                       u16* __restrict__ h, float* __restrict__ c) {
    int wid = (blockIdx.x * 256 + threadIdx.x) >> 6;
    int lane = threadIdx.x & 63;
    int b = wid >> 10, j = wid & 1023;
    bool is_h = j < DEC;
    int jj = is_h ? j : j - DEC;
    const float* W = is_h ? Wh0 : Wc0;
    const float* mrow = mean + b * ENC;
    const float* wrow = W + (size_t)jj * ENC;
    float acc = 0.f;
    #pragma unroll
    for (int kk = 0; kk < 4; kk++) {
        int k = kk * 512 + lane * 8;
        float4 a0 = *reinterpret_cast<const float4*>(mrow + k);
        float4 a1 = *reinterpret_cast<const float4*>(mrow + k + 4);
        float4 w0 = *reinterpret_cast<const float4*>(wrow + k);
        float4 w1 = *reinterpret_cast<const float4*>(wrow + k + 4);
        acc += a0.x * w0.x + a0.y * w0.y + a0.z * w0.z + a0.w * w0.w;
        acc += a1.x * w1.x + a1.y * w1.y + a1.z * w1.z + a1.w * w1.w;
    }
    acc = wave_sum(acc);
    if (lane == 0) {
        acc += is_h ? bh0[jj] : bc0[jj];
        if (is_h) h[b * DEC + jj] = f2bf(acc);
        else      c[b * DEC + jj] = acc;
    }
}

// ---- once: att1 = enc @ We^T + be -> fp32 [B*P, ATT]  (MFMA, bf16 operands) ----
__global__ void k_att1(const u16* __restrict__ enc, const u16* __restrict__ We,
                       const float* __restrict__ be, float* __restrict__ att1) {
    int wid  = (blockIdx.x * 256 + threadIdx.x) >> 6;   // 12544 waves
    int lane = threadIdx.x & 63;
    int nt = wid & 31, mt = wid >> 5;                   // mt 0..391
    int quad = lane >> 4, l16 = lane & 15;
    int m = mt * 16 + l16, n = nt * 16 + l16;
    f32x4 acc = {0.f, 0.f, 0.f, 0.f};
    for (int ks = 0; ks < 64; ks++) {
        int k = ks * 32 + quad * 8;
        bf16x8 a  = *reinterpret_cast<const bf16x8*>(enc + (size_t)m * ENC + k);
        bf16x8 bb = *reinterpret_cast<const bf16x8*>(We  + (size_t)n * ENC + k);
        acc = __builtin_amdgcn_mfma_f32_16x16x32_bf16(a, bb, acc, 0, 0, 0);
    }
    #pragma unroll
    for (int r = 0; r < 4; r++) {
        int mm = mt * 16 + quad * 4 + r, nn = nt * 16 + l16;
        att1[(size_t)mm * ATT + nn] = acc[r] + be[nn];
    }
}

// ---- per step: att2 = h @ Wd^T + bd -> fp32 [B,ATT] (wave per output) ----
__global__ void k_att2(const u16* __restrict__ h, const float* __restrict__ Wd,
                       const float* __restrict__ bd, float* __restrict__ att2) {
    int wid = (blockIdx.x * 256 + threadIdx.x) >> 6;    // 16384 waves
    int lane = threadIdx.x & 63;
    int b = wid >> 9, a = wid & 511;
    bf16x8 hv = *reinterpret_cast<const bf16x8*>(h + b * DEC + lane * 8);
    const float4* wd = reinterpret_cast<const float4*>(Wd + (size_t)a * DEC + lane * 8);
    float4 w0 = wd[0], w1 = wd[1];
    float acc = (float)hv[0] * w0.x + (float)hv[1] * w0.y + (float)hv[2] * w0.z + (float)hv[3] * w0.w
              + (float)hv[4] * w1.x + (float)hv[5] * w1.y + (float)hv[6] * w1.z + (float)hv[7] * w1.w;
    acc = wave_sum(acc);
    if (lane == 0) att2[b * ATT + a] = acc + bd[a];
}

// ---- per step: e[b,p] = sum_a relu(att1+att2)*Wf + bf (wave per (b,p)) ----
__global__ void k_e(const float* __restrict__ att1, const float* __restrict__ att2,
                    const float* __restrict__ Wf, const float* __restrict__ bf,
                    float* __restrict__ e) {
    int wid = (blockIdx.x * 256 + threadIdx.x) >> 6;    // 6272 waves
    int lane = threadIdx.x & 63;
    int b = wid / P, p = wid % P;
    const float* a1 = att1 + ((size_t)b * P + p) * ATT + lane * 8;
    const float* a2 = att2 + b * ATT + lane * 8;
    const float* wf = Wf + lane * 8;
    float acc = 0.f;
    #pragma unroll
    for (int j = 0; j < 8; j++) {
        float v = a1[j] + a2[j];
        v = v > 0.f ? v : 0.f;
        acc += v * wf[j];
    }
    acc = wave_sum(acc);
    if (lane == 0) e[b * P + p] = acc + bf[0];
}

// ---- per step: softmax over P; alpha fp32 ws + alphas output f32 ----
__global__ void k_softmax(const float* __restrict__ e, float* __restrict__ alpha,
                          float* __restrict__ out_alpha, int t) {
    __shared__ float sm[256];
    int b = blockIdx.x, tid = threadIdx.x;
    float v = (tid < P) ? e[b * P + tid] : -1e30f;
    sm[tid] = v; __syncthreads();
    for (int s = 128; s > 0; s >>= 1) { if (tid < s) sm[tid] = fmaxf(sm[tid], sm[tid + s]); __syncthreads(); }
    float mx = sm[0]; __syncthreads();
    float ev = (tid < P) ? expf(v - mx) : 0.f;
    sm[tid] = ev; __syncthreads();
    for (int s = 128; s > 0; s >>= 1) { if (tid < s) sm[tid] += sm[tid + s]; __syncthreads(); }
    float inv = 1.0f / sm[0];
    if (tid < P) {
        float a = ev * inv;
        alpha[b * P + tid] = a;
        out_alpha[(size_t)b * T * P + (size_t)t * P + tid] = a;
    }
}

// ---- per step: awe + build x = [emb_t, awe] as bf16 [B, E+ENC] ----
__global__ void k_awe(const float* __restrict__ alpha, const u16* __restrict__ enc_bf,
                      const float* __restrict__ emb, const int* __restrict__ captions,
                      u16* __restrict__ x, int t) {
    __shared__ float al[P];
    int b = blockIdx.x >> 3, chunk = blockIdx.x & 7, tid = threadIdx.x;
    if (tid < P) al[tid] = alpha[b * P + tid];
    __syncthreads();
    int ec = chunk * 256 + tid;
    const u16* ep = enc_bf + (size_t)b * P * ENC + ec;
    float acc = 0.f;
    for (int p = 0; p < P; p++) acc += al[p] * bf2f(ep[(size_t)p * ENC]);
    x[b * (E + ENC) + E + ec] = f2bf(acc);
    if (chunk == 0) {
        int cap = captions[b * L + t];
        x[b * (E + ENC) + tid] = f2bf(emb[(size_t)cap * E + tid]);
    }
}

// ---- per step: gates = x@Wih^T + h@Whh^T + biases -> fp32 [B, 4*DEC] (MFMA) ----
__global__ void k_gates(const u16* __restrict__ x, const u16* __restrict__ h,
                        const u16* __restrict__ Wih, const float* __restrict__ bih,
                        const u16* __restrict__ Whh, const float* __restrict__ bhh,
                        float* __restrict__ gates) {
    int wid  = (blockIdx.x * 256 + threadIdx.x) >> 6;   // 256 waves
    int lane = threadIdx.x & 63;
    int nt = wid & 127, mt = wid >> 7;
    int quad = lane >> 4, l16 = lane & 15;
    int m = mt * 16 + l16, n = nt * 16 + l16;
    f32x4 acc = {0.f, 0.f, 0.f, 0.f};
    const int KX = E + ENC;                             // 2304
    for (int ks = 0; ks < KX / 32; ks++) {
        int k = ks * 32 + quad * 8;
        bf16x8 a  = *reinterpret_cast<const bf16x8*>(x   + m * KX + k);
        bf16x8 bb = *reinterpret_cast<const bf16x8*>(Wih + (size_t)n * KX + k);
        acc = __builtin_amdgcn_mfma_f32_16x16x32_bf16(a, bb, acc, 0, 0, 0);
    }
    for (int ks = 0; ks < DEC / 32; ks++) {
        int k = ks * 32 + quad * 8;
        bf16x8 a  = *reinterpret_cast<const bf16x8*>(h   + m * DEC + k);
        bf16x8 bb = *reinterpret_cast<const bf16x8*>(Whh + (size_t)n * DEC + k);
        acc = __builtin_amdgcn_mfma_f32_16x16x32_bf16(a, bb, acc, 0, 0, 0);
    }
    #pragma unroll
    for (int r = 0; r < 4; r++) {
        int mm = mt * 16 + quad * 4 + r, nn = nt * 16 + l16;
        gates[mm * (4 * DEC) + nn] = acc[r] + bih[nn] + bhh[nn];
    }
}

// ---- per step: LSTM cell ----
__global__ void k_cell(const float* __restrict__ gates, float* __restrict__ c,
                       u16* __restrict__ h) {
    int idx = blockIdx.x * 256 + threadIdx.x;           // 16384
    int b = idx >> 9, d = idx & 511;
    const float* g = gates + b * (4 * DEC);
    float gi = sigf(g[d]);
    float gf = sigf(g[DEC + d]);
    float gg = tanhf(g[2 * DEC + d]);
    float go = sigf(g[3 * DEC + d]);
    float cn = gf * c[idx] + gi * gg;
    c[idx] = cn;
    h[idx] = f2bf(go * tanhf(cn));
}

// ---- per step: preds = h@Wfc^T + bfc -> f32 output [b, t, v] (MFMA) ----
__global__ void k_preds(const u16* __restrict__ h, const u16* __restrict__ Wfc,
                        const float* __restrict__ bfc, float* __restrict__ out, int t) {
    int wid  = (blockIdx.x * 256 + threadIdx.x) >> 6;   // up to 3752 waves
    int lane = threadIdx.x & 63;
    if (wid >= 2 * (V / 16)) return;                    // 3750 valid
    int nt = wid % (V / 16), mt = wid / (V / 16);
    int quad = lane >> 4, l16 = lane & 15;
    int m = mt * 16 + l16, n = nt * 16 + l16;
    f32x4 acc = {0.f, 0.f, 0.f, 0.f};
    for (int ks = 0; ks < DEC / 32; ks++) {
        int k = ks * 32 + quad * 8;
        bf16x8 a  = *reinterpret_cast<const bf16x8*>(h   + m * DEC + k);
        bf16x8 bb = *reinterpret_cast<const bf16x8*>(Wfc + (size_t)n * DEC + k);
        acc = __builtin_amdgcn_mfma_f32_16x16x32_bf16(a, bb, acc, 0, 0, 0);
    }
    #pragma unroll
    for (int r = 0; r < 4; r++) {
        int mm = mt * 16 + quad * 4 + r, nn = nt * 16 + l16;
        out[(size_t)mm * T * V + (size_t)t * V + nn] = acc[r] + bfc[nn];
    }
}

extern "C" void kernel_launch(void* const* d_in, const int* in_sizes, int n_in,
                              void* d_out, int out_size, void* d_ws, size_t ws_size,
                              hipStream_t stream) {
    const float* enc  = (const float*)d_in[0];
    const int*   caps = (const int*)d_in[1];
    // d_in[2] caption_lengths: unused by reference output
    const float* emb  = (const float*)d_in[3];
    const float* We   = (const float*)d_in[4];
    const float* be   = (const float*)d_in[5];
    const float* Wd   = (const float*)d_in[6];
    const float* bd   = (const float*)d_in[7];
    const float* Wf   = (const float*)d_in[8];
    const float* bfa  = (const float*)d_in[9];
    const float* Wih  = (const float*)d_in[10];
    const float* bih  = (const float*)d_in[11];
    const float* Whh  = (const float*)d_in[12];
    const float* bhh  = (const float*)d_in[13];
    const float* Wfc  = (const float*)d_in[14];
    const float* bfc  = (const float*)d_in[15];
    const float* Wh0  = (const float*)d_in[16];
    const float* bh0  = (const float*)d_in[17];
    const float* Wc0  = (const float*)d_in[18];
    const float* bc0  = (const float*)d_in[19];

    float* out_preds = (float*)d_out;
    float* out_alpha = (float*)d_out + (size_t)B * T * V;

    // workspace carve-up (256B aligned chunks)
    char* w = (char*)d_ws;
    size_t off = 0;
    auto carve = [&](size_t bytes) -> void* {
        void* p = w + off;
        off = (off + bytes + 255) & ~(size_t)255;
        return p;
    };
    u16*   enc_bf = (u16*)  carve((size_t)B * P * ENC * 2);     // 25.7 MB
    u16*   We_bf  = (u16*)  carve((size_t)ATT * ENC * 2);       //  2.1 MB
    u16*   Wih_bf = (u16*)  carve((size_t)4 * DEC * (E + ENC) * 2); // 9.4 MB
    u16*   Whh_bf = (u16*)  carve((size_t)4 * DEC * DEC * 2);   //  2.1 MB
    u16*   Wfc_bf = (u16*)  carve((size_t)V * DEC * 2);         // 30.7 MB
    float* att1   = (float*)carve((size_t)B * P * ATT * 4);     // 12.85 MB
    float* meanb  = (float*)carve((size_t)B * ENC * 4);
    float* att2   = (float*)carve((size_t)B * ATT * 4);
    float* ebuf   = (float*)carve((size_t)B * P * 4);
    float* alpha  = (float*)carve((size_t)B * P * 4);
    u16*   xbuf   = (u16*)  carve((size_t)B * (E + ENC) * 2);
    u16*   hbuf   = (u16*)  carve((size_t)B * DEC * 2);
    float* cbuf   = (float*)carve((size_t)B * DEC * 4);
    float* gates  = (float*)carve((size_t)B * 4 * DEC * 4);
    (void)ws_size; (void)n_in; (void)in_sizes; (void)out_size;

    // one-time: bf16 conversions (element counts all divisible by 1024)
    k_f2b4<<<(B * P * ENC) / 1024, 256, 0, stream>>>(enc, enc_bf, (B * P * ENC) / 4);
    k_f2b4<<<(ATT * ENC) / 1024, 256, 0, stream>>>(We, We_bf, (ATT * ENC) / 4);
    k_f2b4<<<(4 * DEC * (E + ENC)) / 1024, 256, 0, stream>>>(Wih, Wih_bf, (4 * DEC * (E + ENC)) / 4);
    k_f2b4<<<(4 * DEC * DEC) / 1024, 256, 0, stream>>>(Whh, Whh_bf, (4 * DEC * DEC) / 4);
    k_f2b4<<<(V * DEC) / 1024, 256, 0, stream>>>(Wfc, Wfc_bf, (V * DEC) / 4);

    // init phase
    k_mean<<<(B * ENC) / 256, 256, 0, stream>>>(enc, meanb);
    k_h0c0<<<(B * 2 * DEC * 64) / 256, 256, 0, stream>>>(meanb, Wh0, bh0, Wc0, bc0, hbuf, cbuf);
    k_att1<<<((B * P / 16) * (ATT / 16)) / 4, 256, 0, stream>>>(enc_bf, We_bf, be, att1);

    // 20 sequential decode steps
    for (int t = 0; t < T; t++) {
        k_att2   <<<(B * ATT * 64) / 256, 256, 0, stream>>>(hbuf, Wd, bd, att2);
        k_e      <<<(B * P * 64) / 256, 256, 0, stream>>>(att1, att2, Wf, bfa, ebuf);
        k_softmax<<<B, 256, 0, stream>>>(ebuf, alpha, out_alpha, t);
        k_awe    <<<B * 8, 256, 0, stream>>>(alpha, enc_bf, emb, caps, xbuf, t);
        k_gates  <<<(2 * (4 * DEC / 16)) / 4, 256, 0, stream>>>(xbuf, hbuf, Wih_bf, bih, Whh_bf, bhh, gates);
        k_cell   <<<(B * DEC) / 256, 256, 0, stream>>>(gates, cbuf, hbuf);
        k_preds  <<<(2 * (V / 16) + 3) / 4, 256, 0, stream>>>(hbuf, Wfc_bf, bfc, out_preds, t);
    }
}